// Round 7
// baseline (1119.975 us; speedup 1.0000x reference)
//
#include <hip/hip_runtime.h>

// ============================================================================
// Bidirectional LSTM encoder, MI355X.  R7: 16 wgs/dir recurrence + fused prep.
//   - 2 groups (fwd/bwd) x 16 wgs; each wg owns 128 z-cols = one 32-unit
//     K-slice. Exchange image layout & MFMA fragment algebra unchanged vs R6.
//   - tag-in-data sync (dword = bf16<<16 | step), 8-chunk verify/retry reader.
//   - single-buffered astage/zbuf (65 KB LDS), deferred out-stores.
//   - fused prep kernel (aemb+wt+ut+misc); ingemm 256-col tiles.
// ============================================================================

typedef unsigned short u16;
typedef unsigned int   u32;
typedef u16   u16x8 __attribute__((ext_vector_type(8)));
typedef u16   u16x4 __attribute__((ext_vector_type(4)));
typedef u32   u32x4 __attribute__((ext_vector_type(4)));
typedef __bf16 bf16x8 __attribute__((ext_vector_type(8)));
typedef float f32x4 __attribute__((ext_vector_type(4)));

#define EP 320            // padded E (300 -> 320)
#define NC 4096           // 2 dirs * 4H

static const size_t OFF_AEMB = 0;                              // 8192*320*2
static const size_t OFF_WPT  = OFF_AEMB + (size_t)8192*EP*2;
static const size_t OFF_BIAS = OFF_WPT  + (size_t)NC*EP*2;     // f32[4096]
static const size_t OFF_UPT  = OFF_BIAS + (size_t)NC*4;        // bf16 [4096][512]
static const size_t OFF_MASK = OFF_UPT  + (size_t)NC*512*2;    // u32 [32][8]
static const size_t OFF_HIMG = OFF_MASK + 1024;                // u32 2dir*2par*16384 dwords
static const size_t OFF_XW   = OFF_HIMG + (size_t)2*2*16384*4; // bf16 [8192][4096]

__device__ __forceinline__ u16 f2bf(float f){               // RNE
  u32 u = __builtin_bit_cast(u32, f);
  return (u16)((u + 0x7FFFu + ((u >> 16) & 1u)) >> 16);
}
__device__ __forceinline__ float bf2f(u16 h){
  u32 u = ((u32)h) << 16; return __builtin_bit_cast(float, u);
}
__device__ __forceinline__ float sigm(float x){ return 1.f/(1.f+__expf(-x)); }
__device__ __forceinline__ float tanh_(float x){ return 2.f/(1.f+__expf(-2.f*x)) - 1.f; }

// ---------------------------------------------------------------- fused prep
// blocks: [0,8192) aemb | [8192,8256) W-transpose | [8256,8384) U-transpose |
//         [8384,8641) mask + tagged h-image init
__global__ __launch_bounds__(320) void k_prep(const int* __restrict__ x,
                                              const float* __restrict__ emb,
                                              const float* __restrict__ Wf, const float* __restrict__ Wb,
                                              const float* __restrict__ bfv, const float* __restrict__ bbv,
                                              const float* __restrict__ Uf, const float* __restrict__ Ub,
                                              const float* __restrict__ h0f, const float* __restrict__ h0b,
                                              u16* __restrict__ aemb, u16* __restrict__ wpt,
                                              float* __restrict__ bias, u16* __restrict__ upt,
                                              u32* __restrict__ maskb, u32* __restrict__ himg){
  __shared__ u16 lbuf[320*64];                 // 40 KB, reused by wt/ut parts
  int bid = blockIdx.x, tid = threadIdx.x;

  if (bid < 8192){                             // ---- aemb gather
    int m = bid, k = tid;
    int b = m & 31, t = m >> 5;
    int tok = x[b*256 + t];
    float v = (k < 300) ? emb[(size_t)tok*300 + k] : 0.f;
    aemb[(size_t)m*EP + k] = f2bf(v);
    return;
  }
  if (bid < 8256){                             // ---- W -> [col'][K] + bias
    int b2 = bid - 8192;                       // 0..63
    u16 (*lds)[64] = (u16(*)[64])lbuf;
    int c0 = b2*64; int dir = c0 >> 11;
    const float* W = dir ? Wb : Wf;
    if (tid < 256){
      int cl = tid & 63, rr = tid >> 6;
      int ci = (c0 + cl) & 2047; int srccol = (ci & 3)*512 + (ci >> 2);
      for (int kk = 0; kk < 80; kk++){
        int row = kk*4 + rr;
        float v = (row < 300) ? W[(size_t)row*2048 + srccol] : 0.f;
        lds[row][cl] = f2bf(v);
      }
    }
    __syncthreads();
    if (tid < 256){
      int cw = tid >> 2, kc = tid & 3;
      #pragma unroll
      for (int j = 0; j < 10; j++){
        u16x8 v;
        #pragma unroll
        for (int e = 0; e < 8; e++) v[e] = lds[kc*80 + j*8 + e][cw];
        *(u16x8*)&wpt[(size_t)(c0+cw)*EP + kc*80 + j*8] = v;
      }
      if (tid < 64){
        int ci2 = (c0 + tid) & 2047; int sc = (ci2 & 3)*512 + (ci2 >> 2);
        bias[c0 + tid] = (dir ? bbv : bfv)[sc];
      }
    }
    return;
  }
  if (bid < 8384){                             // ---- U -> [col'][K]
    int b2 = bid - 8256;                       // 0..127
    u16 (*lds)[32] = (u16(*)[32])lbuf;
    int cg0 = b2*32; int dir = cg0 >> 11;
    const float* U = dir ? Ub : Uf;
    if (tid < 256){
      int cl = tid & 31, rr = tid >> 5;
      int ci = (cg0 + cl) & 2047; int srccol = (ci & 3)*512 + (ci >> 2);
      for (int kk = 0; kk < 64; kk++){
        int row = kk*8 + rr;
        lds[row][cl] = f2bf(U[(size_t)row*2048 + srccol]);
      }
    }
    __syncthreads();
    if (tid < 256){
      int cw = tid >> 3, kc = tid & 7;
      #pragma unroll
      for (int j = 0; j < 8; j++){
        u16x8 v;
        #pragma unroll
        for (int e = 0; e < 8; e++) v[e] = lds[kc*64 + j*8 + e][cw];
        *(u16x8*)&upt[(size_t)(cg0+cw)*512 + kc*64 + j*8] = v;
      }
    }
    return;
  }
  {                                            // ---- mask + tagged image init
    int b2 = bid - 8384;                       // 0..256
    if (tid >= 256) return;
    if (b2 == 256){
      int b = tid >> 3, w = tid & 7;
      u32 m = 0;
      for (int i = 0; i < 32; i++){ int t = w*32 + i; m |= (u32)(x[b*256 + t] != 0) << i; }
      maskb[b*8 + w] = m;
      return;
    }
    int idx = b2*256 + tid;                    // 0 .. 65535
    int dir = idx >> 15, rem = idx & 32767, par = rem >> 14, di = rem & 16383;
    u32* img = himg + (size_t)dir*32768 + (size_t)par*16384;
    if (par == 0){
      img[di] = 0x0000DEADu;                   // invalid tag
    } else {
      int j = di & 7, lane2 = (di >> 3) & 63, ks = (di >> 9) & 15, mt = di >> 13;
      int b = mt*16 + (lane2 & 15), ug = ks*32 + (lane2 >> 4)*8 + j;
      const float* h0 = dir ? h0b : h0f;
      img[di] = ((u32)f2bf(h0[b*512 + ug]) << 16) | 0xFFFFu;   // h_{-1}, tag -1
    }
  }
}

// ---------------------------------------------------------------- input GEMM: xW+b (bf16 MFMA)
__global__ __launch_bounds__(512) void k_ingemm(const u16* __restrict__ aemb, const u16* __restrict__ wpt,
                                                const float* __restrict__ bias, u16* __restrict__ xw){
  int bx = blockIdx.x, by = blockIdx.y;        // 64 x 16
  int tid = threadIdx.x, lane = tid & 63, wv = tid >> 6;
  int m0 = bx*128 + wv*16;
  u16x8 afr[10];
  const u16* ap = aemb + (size_t)(m0 + (lane & 15))*EP + ((lane >> 4)*8);
  #pragma unroll
  for (int ks = 0; ks < 10; ks++) afr[ks] = *(const u16x8*)(ap + ks*32);
  #pragma unroll
  for (int n = 0; n < 16; n++){
    int colp = by*256 + n*16 + (lane & 15);
    const u16* bp = wpt + (size_t)colp*EP + ((lane >> 4)*8);
    f32x4 acc = {0.f, 0.f, 0.f, 0.f};
    #pragma unroll
    for (int ks = 0; ks < 10; ks++){
      bf16x8 bfr = __builtin_bit_cast(bf16x8, *(const u16x8*)(bp + ks*32));
      acc = __builtin_amdgcn_mfma_f32_16x16x32_bf16(__builtin_bit_cast(bf16x8, afr[ks]), bfr, acc, 0, 0, 0);
    }
    float bv = bias[colp];
    #pragma unroll
    for (int v = 0; v < 4; v++){
      int m = m0 + (lane >> 4)*4 + v;          // C/D: col=lane&15, row=(lane>>4)*4+reg  [m89]
      xw[(size_t)m*NC + colp] = f2bf(acc[v] + bv);
    }
  }
}

// ---------------------------------------------------------------- persistent recurrence
__global__ __launch_bounds__(512, 2) void k_recur(const u16* __restrict__ xw, const u16* __restrict__ upt,
                                                  const u32* __restrict__ maskb, u32* __restrict__ himg,
                                                  const float* __restrict__ c0f, const float* __restrict__ c0b,
                                                  const float* __restrict__ h0f, const float* __restrict__ h0b,
                                                  float* __restrict__ out){
  int bid = blockIdx.x;                        // 32 wgs
  int dir = bid & 1, r = bid >> 1;             // direction, rank in group (0..15)
  int tid = threadIdx.x, lane = tid & 63, wv = tid >> 6;
  int nw = wv & 3, kh = wv >> 2;               // wave's col-tile pair and K-half

  __shared__ u16   astage[16384];              // bf16 frag image, 32 KB (single buf)
  __shared__ float zbuf[2][32][128];           // [khalf][b][local col], 32 KB
  __shared__ u32   mk[32][8];

  // U-slice as persistent B-fragments: cols r*128 + (nw+4n)*16 + (lane&15)
  bf16x8 bfr0[8], bfr1[8];
  {
    const u16* ub0 = upt + ((size_t)dir*2048 + r*128 + nw*16       + (lane & 15))*512 + ((lane >> 4)*8);
    const u16* ub1 = upt + ((size_t)dir*2048 + r*128 + (nw+4)*16   + (lane & 15))*512 + ((lane >> 4)*8);
    #pragma unroll
    for (int i = 0; i < 8; i++){
      int ks = kh*8 + i;
      bfr0[i] = __builtin_bit_cast(bf16x8, *(const u16x8*)(ub0 + ks*32));
      bfr1[i] = __builtin_bit_cast(bf16x8, *(const u16x8*)(ub1 + ks*32));
    }
  }
  int b = tid >> 4, u2 = tid & 15;             // gate thread: batch b, units u2 & u2+16
  float c_reg[2], h_reg[2];
  int ugl[2];
  #pragma unroll
  for (int e = 0; e < 2; e++){
    int ul = u2 + e*16;
    ugl[e] = r*32 + ul;
    c_reg[e] = (dir ? c0b : c0f)[b*512 + ugl[e]];
    h_reg[e] = (dir ? h0b : h0f)[b*512 + ugl[e]];
  }
  if (tid < 256) mk[tid >> 3][tid & 7] = maskb[tid];
  __syncthreads();

  u32* img = himg + (size_t)dir*32768;
  size_t dpub[2];
  #pragma unroll
  for (int e = 0; e < 2; e++){
    int ul = u2 + e*16;
    dpub[e] = (((size_t)(b >> 4)*16 + r)*64 + (size_t)((ul >> 3)*16 + (b & 15)))*8 + (ul & 7);
  }

  int t0 = dir ? 255 : 0;
  u16x4 pref[2];
  #pragma unroll
  for (int e = 0; e < 2; e++)
    pref[e] = *(const u16x4*)(xw + (size_t)(t0*32 + b)*NC + dir*2048 + r*128 + (u2 + e*16)*4);

  for (int s = 0; s < 256; ++s){
    int t = dir ? 255 - s : s;
    int sn = (s < 255) ? s + 1 : s;
    int tn = dir ? 255 - sn : sn;

    // ---- stage + verify: 8 tagged 16B chunks/thread (full 64KB image), retry
    u32 tg = (u32)((s - 1) & 0xFFFF);
    int pr = (s + 1) & 1;
    const char* gsrc = (const char*)(img + (size_t)pr*16384) + (size_t)tid*16;
    u32x4 v0, v1, v2, v3, v4, v5, v6, v7;
    #define LD(i) asm volatile("global_load_dwordx4 %0, %1, off sc0 sc1" : "=v"(v##i) : "v"(gsrc + i*8192))
    LD(0); LD(1); LD(2); LD(3); LD(4); LD(5); LD(6); LD(7);

    u16x4 nxt[2];
    #pragma unroll
    for (int e = 0; e < 2; e++)
      nxt[e] = *(const u16x4*)(xw + (size_t)(tn*32 + b)*NC + dir*2048 + r*128 + (u2 + e*16)*4);

    u32 pend = 255u;
    for (;;){
      asm volatile("s_waitcnt vmcnt(0)" ::: "memory");
      __builtin_amdgcn_sched_barrier(0);
      #define CK(i) if (pend & (1u << i)){ \
        if ((((v##i.x ^ tg) | (v##i.y ^ tg) | (v##i.z ^ tg) | (v##i.w ^ tg)) & 0xFFFFu) == 0u){ \
          u16x4 p; p[0] = (u16)(v##i.x >> 16); p[1] = (u16)(v##i.y >> 16); \
                   p[2] = (u16)(v##i.z >> 16); p[3] = (u16)(v##i.w >> 16); \
          *(u16x4*)((char*)&astage[0] + (size_t)tid*8 + i*4096) = p; \
          pend &= ~(1u << i); \
        } else { LD(i); } }
      CK(0); CK(1); CK(2); CK(3); CK(4); CK(5); CK(6); CK(7);
      #undef CK
      if (!pend) break;
    }
    #undef LD

    // ---- deferred out-store of h_{s-1} (overlaps barrier/MFMA phase)
    if (s > 0){
      int tp = dir ? 256 - s : s - 1;
      #pragma unroll
      for (int e = 0; e < 2; e++)
        out[(size_t)(b*256 + tp)*1024 + dir*512 + ugl[e]] = h_reg[e];
    }
    __syncthreads();                            // (B) astage ready

    // ---- z = h_{s-1} @ U : 32 MFMA per wave
    f32x4 acc00 = {0.f,0.f,0.f,0.f}, acc01 = {0.f,0.f,0.f,0.f};
    f32x4 acc10 = {0.f,0.f,0.f,0.f}, acc11 = {0.f,0.f,0.f,0.f};
    {
      const u16* ab = &astage[0] + lane*8;
      #pragma unroll
      for (int i = 0; i < 8; i++){
        int ks = kh*8 + i;
        bf16x8 a0 = __builtin_bit_cast(bf16x8, *(const u16x8*)(ab + (size_t)ks*512));
        bf16x8 a1 = __builtin_bit_cast(bf16x8, *(const u16x8*)(ab + (size_t)(16 + ks)*512));
        acc00 = __builtin_amdgcn_mfma_f32_16x16x32_bf16(a0, bfr0[i], acc00, 0, 0, 0);
        acc01 = __builtin_amdgcn_mfma_f32_16x16x32_bf16(a0, bfr1[i], acc01, 0, 0, 0);
        acc10 = __builtin_amdgcn_mfma_f32_16x16x32_bf16(a1, bfr0[i], acc10, 0, 0, 0);
        acc11 = __builtin_amdgcn_mfma_f32_16x16x32_bf16(a1, bfr1[i], acc11, 0, 0, 0);
      }
      int row0 = (lane >> 4)*4;
      int cc0 = nw*16 + (lane & 15), cc1 = (nw+4)*16 + (lane & 15);
      #pragma unroll
      for (int v = 0; v < 4; v++){
        zbuf[kh][row0 + v][cc0]      = acc00[v];
        zbuf[kh][row0 + v][cc1]      = acc01[v];
        zbuf[kh][16 + row0 + v][cc0] = acc10[v];
        zbuf[kh][16 + row0 + v][cc1] = acc11[v];
      }
    }
    __syncthreads();                            // (C) zbuf ready

    // ---- gate stage: thread (b, u2) handles units u2 and u2+16
    #pragma unroll
    for (int e = 0; e < 2; e++){
      int ul = u2 + e*16;
      f32x4 za = *(const f32x4*)&zbuf[0][b][ul*4];
      f32x4 zc = *(const f32x4*)&zbuf[1][b][ul*4];
      float zi = za[0] + zc[0] + bf2f(pref[e][0]);
      float zf = za[1] + zc[1] + bf2f(pref[e][1]);
      float zg = za[2] + zc[2] + bf2f(pref[e][2]);
      float zo = za[3] + zc[3] + bf2f(pref[e][3]);
      float gi = sigm(zi), gf = sigm(zf), gg = tanh_(zg), go = sigm(zo);
      float cn = gf*c_reg[e] + gi*gg;
      float hn = go*tanh_(cn);
      if ((mk[b][t >> 5] >> (t & 31)) & 1){ c_reg[e] = cn; h_reg[e] = hn; }

      if (s < 255){                             // publish immediately
        u32 dw = ((u32)f2bf(h_reg[e]) << 16) | (u32)s;
        u32* gdst = img + (size_t)(s & 1)*16384 + dpub[e];
        asm volatile("global_store_dword %0, %1, off sc0 sc1" :: "v"(gdst), "v"(dw) : "memory");
      }
      pref[e] = nxt[e];
    }
  }

  // ---- finals: last timestep output + h/c state vectors
  int tl = dir ? 0 : 255;
  #pragma unroll
  for (int e = 0; e < 2; e++){
    out[(size_t)(b*256 + tl)*1024 + dir*512 + ugl[e]] = h_reg[e];
    out[8388608 + dir*16384 + b*512 + ugl[e]] = h_reg[e];                 // h_f / h_b
    out[8388608 + 32768 + dir*16384 + b*512 + ugl[e]] = c_reg[e];         // c_f / c_b
  }
}

// ----------------------------------------------------------------------------
extern "C" void kernel_launch(void* const* d_in, const int* in_sizes, int n_in,
                              void* d_out, int out_size, void* d_ws, size_t ws_size,
                              hipStream_t stream){
  const int*   x   = (const int*)  d_in[0];
  const float* h0f = (const float*)d_in[1];
  const float* c0f = (const float*)d_in[2];
  const float* h0b = (const float*)d_in[3];
  const float* c0b = (const float*)d_in[4];
  const float* emb = (const float*)d_in[5];
  const float* Wf  = (const float*)d_in[6];
  const float* Uf  = (const float*)d_in[7];
  const float* bfv = (const float*)d_in[8];
  const float* Wb  = (const float*)d_in[9];
  const float* Ub  = (const float*)d_in[10];
  const float* bbv = (const float*)d_in[11];
  float* out = (float*)d_out;

  char* w = (char*)d_ws;
  u16*   aemb = (u16*)(w + OFF_AEMB);
  u16*   wpt  = (u16*)(w + OFF_WPT);
  float* bias = (float*)(w + OFF_BIAS);
  u16*   upt  = (u16*)(w + OFF_UPT);
  u32*   mskb = (u32*)(w + OFF_MASK);
  u32*   himg = (u32*)(w + OFF_HIMG);
  u16*   xw   = (u16*)(w + OFF_XW);

  k_prep  <<<dim3(8641),  dim3(320), 0, stream>>>(x, emb, Wf, Wb, bfv, bbv, Uf, Ub,
                                                  h0f, h0b, aemb, wpt, bias, upt, mskb, himg);
  k_ingemm<<<dim3(64,16), dim3(512), 0, stream>>>(aemb, wpt, bias, xw);
  k_recur <<<dim3(32),    dim3(512), 0, stream>>>(xw, upt, mskb, himg,
                                                  c0f, c0b, h0f, h0b, out);
}